// Round 5
// baseline (671.743 us; speedup 1.0000x reference)
//
#include <hip/hip_runtime.h>
#include <hip/hip_bf16.h>
#include <hip/hip_fp16.h>

#define BATCH 16384
#define HID   2048
#define IND   784
#define INDP  832   // 784 padded to 13*64
#define OUTD  10

typedef _Float16 f16;
typedef __attribute__((ext_vector_type(8))) _Float16 f16x8;
typedef __attribute__((ext_vector_type(4))) float f32x4;

// ---- mask dtype detector ----------------------------------------------------
// Scans first nbytes of the mask buffer. Writes flag bits into *flags:
//   bit1: saw a byte value > 1          -> float-encoded mask (use 32-bit word != 0)
//   bit0: saw nonzero byte at off%4!=0  -> genuine 1-byte bool (use byte != 0)
// Resolution in prep_cast: flags==1 -> byte mode, else word mode (int32/float32).
__global__ void mask_detect(const unsigned char* __restrict__ p, int nbytes,
                            int* __restrict__ flags) {
    int acc = 0;
    for (int i = blockIdx.x * blockDim.x + threadIdx.x; i < nbytes;
         i += gridDim.x * blockDim.x) {
        unsigned char b = p[i];
        if (b > 1) acc |= 2;
        else if (b != 0 && (i & 3) != 0) acc |= 1;
    }
    if (acc) atomicOr(flags, acc);
}

// Cast f32 -> fp16 with optional mask (dtype per *flags) and zero padding.
// out is [rout][kout]; src is [rin][kin]; pad region (r>=rin or c>=kin) = 0.
__global__ void prep_cast(const float* __restrict__ W,
                          const void* __restrict__ Mk,
                          const int* __restrict__ flags,
                          f16* __restrict__ out,
                          int rin, int kin, int kout, int total) {
    int idx = blockIdx.x * blockDim.x + threadIdx.x;
    if (idx >= total) return;
    int r = idx / kout, c = idx - r * kout;
    float v = 0.f;
    if (r < rin && c < kin) {
        v = W[(size_t)r * kin + c];
        if (Mk) {
            size_t mi = (size_t)r * kin + c;
            bool byteMode = (*flags == 1);
            bool keep = byteMode ? (((const unsigned char*)Mk)[mi] != 0)
                                 : (((const unsigned int*)Mk)[mi] != 0u);
            if (!keep) v = 0.f;
        }
    }
    out[idx] = (f16)v;   // v_cvt_f16_f32, RTN
}

__device__ __forceinline__ void gload_lds16(const f16* g, f16* l) {
    __builtin_amdgcn_global_load_lds(
        (const __attribute__((address_space(1))) unsigned int*)g,
        (__attribute__((address_space(3))) unsigned int*)l,
        16, 0, 0);
}

// C[M][Nout] = A[M][K] @ B[N][K]^T + bias, optional ReLU.
// m97 structure: 128x128 tile, BK=64, 4 waves (2x2 of 64x64), 16x16x32 f16 MFMA.
// (global_load_lds staging verified bit-identical to reg-staged path in R3/R4.)
template<bool RELU, bool OUTF32>
__global__ __launch_bounds__(256, 3) void gemm_bt(
    const f16* __restrict__ A,
    const f16* __restrict__ B,
    const float* __restrict__ bias,
    void* __restrict__ C,
    int M, int N, int K, int Nout) {
    __shared__ f16 As[128 * 64];
    __shared__ f16 Bs[128 * 64];

    int nbn = N >> 7;
    int bm = blockIdx.x / nbn;
    int bn = blockIdx.x - bm * nbn;

    int t = threadIdx.x;
    int w = t >> 6, lane = t & 63;
    int wm = w >> 1, wn = w & 1;
    int l15 = lane & 15, l4 = lane >> 4;

    const f16* Ag = A + (size_t)bm * 128 * K;
    const f16* Bg = B + (size_t)bn * 128 * K;
    // staging geometry: issue i covers rows [i*32, i*32+32); wave w lane l ->
    // element w*512 + l*8 -> row w*8 + (l>>3), col (l&7)*8. LDS dest is
    // wave-uniform base + lane*16B -> linear [128][64].
    int rr = w * 8 + (lane >> 3);
    int cc = (lane & 7) * 8;

    f32x4 acc[4][4] = {};

    for (int k0 = 0; k0 < K; k0 += 64) {
        #pragma unroll
        for (int i = 0; i < 4; ++i)
            gload_lds16(Ag + (size_t)(i * 32 + rr) * K + k0 + cc,
                        As + i * 2048 + w * 512);
        #pragma unroll
        for (int i = 0; i < 4; ++i)
            gload_lds16(Bg + (size_t)(i * 32 + rr) * K + k0 + cc,
                        Bs + i * 2048 + w * 512);
        __syncthreads();   // drains vmcnt + barrier: tiles ready
        #pragma unroll
        for (int ks = 0; ks < 2; ++ks) {
            f16x8 af[4], bfr[4];
            #pragma unroll
            for (int m = 0; m < 4; ++m)
                af[m] = *(const f16x8*)(As + (wm * 64 + m * 16 + l15) * 64 + ks * 32 + l4 * 8);
            #pragma unroll
            for (int n = 0; n < 4; ++n)
                bfr[n] = *(const f16x8*)(Bs + (wn * 64 + n * 16 + l15) * 64 + ks * 32 + l4 * 8);
            #pragma unroll
            for (int m = 0; m < 4; ++m)
                #pragma unroll
                for (int n = 0; n < 4; ++n)
                    acc[m][n] = __builtin_amdgcn_mfma_f32_16x16x32_f16(
                        af[m], bfr[n], acc[m][n], 0, 0, 0);
        }
        __syncthreads();   // before overwriting LDS next iter
    }

    // Epilogue. C/D layout (m89/m91, dtype-independent): col = lane&15, row = (lane>>4)*4 + reg.
    #pragma unroll
    for (int n = 0; n < 4; ++n) {
        int j = bn * 128 + wn * 64 + n * 16 + l15;
        bool jok = j < Nout;
        float bv = jok ? bias[j] : 0.f;
        #pragma unroll
        for (int m = 0; m < 4; ++m) {
            int i0 = bm * 128 + wm * 64 + m * 16 + l4 * 4;
            #pragma unroll
            for (int r = 0; r < 4; ++r) {
                float v = acc[m][n][r] + bv;
                if (RELU) v = fmaxf(v, 0.f);
                if (OUTF32) {
                    if (jok) ((float*)C)[(size_t)(i0 + r) * Nout + j] = v;
                } else {
                    ((f16*)C)[(size_t)(i0 + r) * Nout + j] = (f16)v;
                }
            }
        }
    }
}

extern "C" void kernel_launch(void* const* d_in, const int* in_sizes, int n_in,
                              void* d_out, int out_size, void* d_ws, size_t ws_size,
                              hipStream_t stream) {
    const float* x  = (const float*)d_in[0];
    const float* W1 = (const float*)d_in[1];
    const float* b1 = (const float*)d_in[2];
    const float* W2 = (const float*)d_in[3];
    const float* b2 = (const float*)d_in[4];
    const float* W3 = (const float*)d_in[5];
    const float* b3 = (const float*)d_in[6];
    const float* W4 = (const float*)d_in[7];
    const float* b4 = (const float*)d_in[8];
    const float* W5 = (const float*)d_in[9];
    const float* b5 = (const float*)d_in[10];
    const void* m1 = d_in[11];
    const void* m2 = d_in[12];
    const void* m3 = d_in[13];
    const void* m4 = d_in[14];

    char* ws = (char*)d_ws;
    size_t off = 0;
    auto alloc = [&](size_t b) { char* p = ws + off; off += (b + 255) & ~(size_t)255; return p; };
    f16* xb  = (f16*)alloc((size_t)BATCH * INDP * 2);   // 27.3 MB
    f16* w1b = (f16*)alloc((size_t)HID * INDP * 2);     //  3.4 MB
    f16* w2b = (f16*)alloc((size_t)HID * HID * 2);      //  8.4 MB
    f16* w3b = (f16*)alloc((size_t)HID * HID * 2);
    f16* w4b = (f16*)alloc((size_t)HID * HID * 2);
    f16* w5b = (f16*)alloc((size_t)128 * HID * 2);      //  0.5 MB
    f16* h1  = (f16*)alloc((size_t)BATCH * HID * 2);    // 67.1 MB
    f16* h2  = (f16*)alloc((size_t)BATCH * HID * 2);    // total ~191 MB
    int* flags = (int*)alloc(256);

    // detect mask dtype from m1's raw bytes (recomputed every call; pure fn of inputs)
    hipMemsetAsync(flags, 0, sizeof(int), stream);
    mask_detect<<<64, 256, 0, stream>>>((const unsigned char*)m1, 262144, flags);

    auto prep = [&](const float* src, const void* mk, f16* dst,
                    int rin, int kin, int kout, int rout) {
        int total = rout * kout;
        prep_cast<<<(total + 255) / 256, 256, 0, stream>>>(src, mk, flags, dst,
                                                           rin, kin, kout, total);
    };
    prep(x,  nullptr, xb,  BATCH, IND, INDP, BATCH);
    prep(W1, m1,      w1b, HID,   IND, INDP, HID);
    prep(W2, m2,      w2b, HID,   HID, HID,  HID);
    prep(W3, m3,      w3b, HID,   HID, HID,  HID);
    prep(W4, m4,      w4b, HID,   HID, HID,  HID);
    prep(W5, nullptr, w5b, OUTD,  HID, HID,  128);

    dim3 blk(256);
    int gmid = (BATCH / 128) * (HID / 128);  // 2048 blocks
    gemm_bt<true,  false><<<gmid, blk, 0, stream>>>(xb, w1b, b1, h1, BATCH, HID, INDP, HID);
    gemm_bt<true,  false><<<gmid, blk, 0, stream>>>(h1, w2b, b2, h2, BATCH, HID, HID,  HID);
    gemm_bt<true,  false><<<gmid, blk, 0, stream>>>(h2, w3b, b3, h1, BATCH, HID, HID,  HID);
    gemm_bt<true,  false><<<gmid, blk, 0, stream>>>(h1, w4b, b4, h2, BATCH, HID, HID,  HID);
    gemm_bt<false, true ><<<BATCH / 128, blk, 0, stream>>>(h2, w5b, b5, d_out, BATCH, 128, HID, OUTD);
}

// Round 6
// 584.911 us; speedup vs baseline: 1.1485x; 1.1485x over previous
//
#include <hip/hip_runtime.h>
#include <hip/hip_bf16.h>
#include <hip/hip_fp16.h>

#define BATCH 16384
#define HID   2048
#define IND   784
#define INDP  896   // 784 padded to 14*64 (even # of 64-wide K-tiles)
#define OUTD  10

typedef _Float16 f16;
typedef __attribute__((ext_vector_type(8))) _Float16 f16x8;
typedef __attribute__((ext_vector_type(4))) float f32x4;

// ---- mask dtype detector (verified R5) -------------------------------------
__global__ void mask_detect(const unsigned char* __restrict__ p, int nbytes,
                            int* __restrict__ flags) {
    int acc = 0;
    for (int i = blockIdx.x * blockDim.x + threadIdx.x; i < nbytes;
         i += gridDim.x * blockDim.x) {
        unsigned char b = p[i];
        if (b > 1) acc |= 2;
        else if (b != 0 && (i & 3) != 0) acc |= 1;
    }
    if (acc) atomicOr(flags, acc);
}

__global__ void prep_cast(const float* __restrict__ W,
                          const void* __restrict__ Mk,
                          const int* __restrict__ flags,
                          f16* __restrict__ out,
                          int rin, int kin, int kout, int total) {
    int idx = blockIdx.x * blockDim.x + threadIdx.x;
    if (idx >= total) return;
    int r = idx / kout, c = idx - r * kout;
    float v = 0.f;
    if (r < rin && c < kin) {
        v = W[(size_t)r * kin + c];
        if (Mk) {
            size_t mi = (size_t)r * kin + c;
            bool byteMode = (*flags == 1);
            bool keep = byteMode ? (((const unsigned char*)Mk)[mi] != 0)
                                 : (((const unsigned int*)Mk)[mi] != 0u);
            if (!keep) v = 0.f;
        }
    }
    out[idx] = (f16)v;
}

__device__ __forceinline__ void gload_lds16(const f16* g, f16* l) {
    __builtin_amdgcn_global_load_lds(
        (const __attribute__((address_space(1))) unsigned int*)g,
        (__attribute__((address_space(3))) unsigned int*)l,
        16, 0, 0);
}

#define BAR()   __builtin_amdgcn_s_barrier()
#define SCHED() __builtin_amdgcn_sched_barrier(0)
#define WAITV4() asm volatile("s_waitcnt vmcnt(4)" ::: "memory")
#define WAITL0() asm volatile("s_waitcnt lgkmcnt(0)" ::: "memory")

// ---- 256x256 8-phase GEMM (T1+T2+T3+T4+T5), C[M][N] = A@B^T + bias, ReLU ---
// BM=BN=256, BK=64, 8 waves (2Mx4N), 512 thr. LDS: A/B x [buf][ks][256][32] f16
// = 128 KiB. Panel = [256][32] (16 KB, 2 gload_lds/phase). Swizzle: within-row
// 16B-slot ^= row&3, pre-swizzled on global src, applied on ds_read (involution).
// Phase p consumes (buf, ks, m-half); panel retired at end of its last-read
// phase, restaged >=1 phase later; vmcnt(4)+barrier at ph4/ph8 guarantees the
// next half-iteration's 4 panels have landed (per-wave ledger: 12 out -> 4).
template<bool RELU>
__global__ __launch_bounds__(512, 2) void gemm8p(
    const f16* __restrict__ A, const f16* __restrict__ B,
    const float* __restrict__ bias, f16* __restrict__ C,
    int N, int K) {
    __shared__ f16 As[2 * 2 * 256 * 32];
    __shared__ f16 Bs[2 * 2 * 256 * 32];

    int nbn = N >> 8;
    int nwg = gridDim.x;
    int cpx = nwg >> 3;                       // nwg % 8 == 0 here
    int bid = blockIdx.x;
    int swz = (bid & 7) * cpx + (bid >> 3);   // XCD-aware, bijective
    int bm = swz / nbn, bn = swz % nbn;

    int tid = threadIdx.x;
    int w = tid >> 6, lane = tid & 63;
    int wr = w >> 2, wc = w & 3;
    int l15 = lane & 15, l4 = lane >> 4;

    const f16* Ag = A + (size_t)bm * 256 * K;
    const f16* Bg = B + (size_t)bn * 256 * K;

    // staging geometry: issue j slot fs=j*512+tid -> row=fs>>2, s=fs&3;
    // global col-slot = s ^ (row&3) (inverse swizzle on source).
    int r0 = tid >> 2, s0 = tid & 3;
    int c0 = (s0 ^ (r0 & 3)) * 8;             // same for j=1 (row+128, &3 same)
    int ldsw0 = (w * 64) * 8;                 // wave-uniform LDS f16 offsets
    int ldsw1 = (512 + w * 64) * 8;

    auto stageA = [&](int buf, int ks, int tk) {
        const f16* s = Ag + (size_t)r0 * K + tk * 64 + ks * 32 + c0;
        gload_lds16(s, As + (buf * 2 + ks) * 8192 + ldsw0);
        const f16* s2 = Ag + (size_t)(128 + r0) * K + tk * 64 + ks * 32 + c0;
        gload_lds16(s2, As + (buf * 2 + ks) * 8192 + ldsw1);
    };
    auto stageB = [&](int buf, int ks, int tk) {
        const f16* s = Bg + (size_t)r0 * K + tk * 64 + ks * 32 + c0;
        gload_lds16(s, Bs + (buf * 2 + ks) * 8192 + ldsw0);
        const f16* s2 = Bg + (size_t)(128 + r0) * K + tk * 64 + ks * 32 + c0;
        gload_lds16(s2, Bs + (buf * 2 + ks) * 8192 + ldsw1);
    };

    int rsw = (l4 ^ (l15 & 3)) * 8;           // swizzled read slot (f16 units)
    auto ldA = [&](f16x8 (&af)[4], int buf, int ks, int mh) {
        int base = (buf * 2 + ks) * 8192;
        #pragma unroll
        for (int m = 0; m < 4; ++m) {
            int row = wr * 128 + (mh * 4 + m) * 16 + l15;
            af[m] = *(const f16x8*)(As + base + row * 32 + rsw);
        }
    };
    auto ldB = [&](f16x8 (&bf)[4], int buf, int ks) {
        int base = (buf * 2 + ks) * 8192;
        #pragma unroll
        for (int n = 0; n < 4; ++n) {
            int row = wc * 64 + n * 16 + l15;
            bf[n] = *(const f16x8*)(Bs + base + row * 32 + rsw);
        }
    };

    f32x4 acc[8][4] = {};
    auto mma = [&](f16x8 (&af)[4], f16x8 (&bf)[4], int mh) {
        __builtin_amdgcn_s_setprio(1);
        #pragma unroll
        for (int m = 0; m < 4; ++m)
            #pragma unroll
            for (int n = 0; n < 4; ++n)
                acc[mh * 4 + m][n] = __builtin_amdgcn_mfma_f32_16x16x32_f16(
                    af[m], bf[n], acc[mh * 4 + m][n], 0, 0, 0);
        __builtin_amdgcn_s_setprio(0);
    };

    int NT = K >> 6, NI = NT >> 1;

    // prologue: tile0 all panels, tile1 A0,B0 (12 issues); oldest 8 must land
    stageA(0, 0, 0); stageB(0, 0, 0); stageA(0, 1, 0); stageB(0, 1, 0);
    stageA(1, 0, 1); stageB(1, 0, 1);
    WAITV4(); SCHED(); BAR();

    for (int it = 0; it < NI; ++it) {
        int t1 = 2 * it + 1, t2 = 2 * it + 2, t3 = 2 * it + 3;
        if (t2 >= NT) t2 = 0;   // tail: stage into retired panels, never read
        if (t3 >= NT) t3 = 0;
        f16x8 a0[4], a1[4], b0[4], b1[4];

        // ph1: buf0 ks0 mh0 | stage buf1.A1 <- t1
        ldA(a0, 0, 0, 0); ldB(b0, 0, 0); stageA(1, 1, t1);
        SCHED(); BAR(); WAITL0(); SCHED();
        mma(a0, b0, 0); BAR();
        // ph2: buf0 ks0 mh1 (reuse b0) | stage buf1.B1 <- t1
        ldA(a1, 0, 0, 1); stageB(1, 1, t1);
        SCHED(); BAR(); WAITL0(); SCHED();
        mma(a1, b0, 1); BAR();
        // ph3: buf0 ks1 mh0 | stage buf0.A0 <- t2
        ldA(a0, 0, 1, 0); ldB(b1, 0, 1); stageA(0, 0, t2);
        SCHED(); BAR(); WAITL0(); SCHED();
        mma(a0, b1, 0); BAR();
        // ph4: buf0 ks1 mh1 | stage buf0.B0 <- t2 | vmcnt(4)
        ldA(a1, 0, 1, 1); stageB(0, 0, t2);
        SCHED(); BAR(); WAITL0(); SCHED();
        mma(a1, b1, 1); WAITV4(); SCHED(); BAR();
        // ph5: buf1 ks0 mh0 | stage buf0.A1 <- t2
        ldA(a0, 1, 0, 0); ldB(b0, 1, 0); stageA(0, 1, t2);
        SCHED(); BAR(); WAITL0(); SCHED();
        mma(a0, b0, 0); BAR();
        // ph6: buf1 ks0 mh1 | stage buf0.B1 <- t2
        ldA(a1, 1, 0, 1); stageB(0, 1, t2);
        SCHED(); BAR(); WAITL0(); SCHED();
        mma(a1, b0, 1); BAR();
        // ph7: buf1 ks1 mh0 | stage buf1.A0 <- t3
        ldA(a0, 1, 1, 0); ldB(b1, 1, 1); stageA(1, 0, t3);
        SCHED(); BAR(); WAITL0(); SCHED();
        mma(a0, b1, 0); BAR();
        // ph8: buf1 ks1 mh1 | stage buf1.B0 <- t3 | vmcnt(4)
        ldA(a1, 1, 1, 1); stageB(1, 0, t3);
        SCHED(); BAR(); WAITL0(); SCHED();
        mma(a1, b1, 1); WAITV4(); SCHED(); BAR();
    }

    // epilogue: C/D layout col=lane&15, row=(lane>>4)*4+reg (m89/m91)
    #pragma unroll
    for (int nf = 0; nf < 4; ++nf) {
        int j = bn * 256 + wc * 64 + nf * 16 + l15;
        float bv = bias[j];
        #pragma unroll
        for (int mf = 0; mf < 8; ++mf) {
            int i0 = bm * 256 + wr * 128 + mf * 16 + l4 * 4;
            #pragma unroll
            for (int r = 0; r < 4; ++r) {
                float v = acc[mf][nf][r] + bv;
                if (RELU) v = fmaxf(v, 0.f);
                C[(size_t)(i0 + r) * N + j] = (f16)v;
            }
        }
    }
}

// ---- head: verified R5 128^2 kernel (Nout=10 guard, f32 out) ---------------
__global__ __launch_bounds__(256, 3) void gemm_head(
    const f16* __restrict__ A, const f16* __restrict__ B,
    const float* __restrict__ bias, float* __restrict__ C,
    int K, int Nout) {
    __shared__ f16 As[128 * 64];
    __shared__ f16 Bs[128 * 64];
    int bm = blockIdx.x;
    int t = threadIdx.x;
    int w = t >> 6, lane = t & 63;
    int wm = w >> 1, wn = w & 1;
    int l15 = lane & 15, l4 = lane >> 4;
    const f16* Ag = A + (size_t)bm * 128 * K;
    const f16* Bg = B;
    int rr = w * 8 + (lane >> 3);
    int cc = (lane & 7) * 8;
    f32x4 acc[4][4] = {};
    for (int k0 = 0; k0 < K; k0 += 64) {
        #pragma unroll
        for (int i = 0; i < 4; ++i)
            gload_lds16(Ag + (size_t)(i * 32 + rr) * K + k0 + cc, As + i * 2048 + w * 512);
        #pragma unroll
        for (int i = 0; i < 4; ++i)
            gload_lds16(Bg + (size_t)(i * 32 + rr) * K + k0 + cc, Bs + i * 2048 + w * 512);
        __syncthreads();
        #pragma unroll
        for (int ks = 0; ks < 2; ++ks) {
            f16x8 af[4], bfr[4];
            #pragma unroll
            for (int m = 0; m < 4; ++m)
                af[m] = *(const f16x8*)(As + (wm * 64 + m * 16 + l15) * 64 + ks * 32 + l4 * 8);
            #pragma unroll
            for (int n = 0; n < 4; ++n)
                bfr[n] = *(const f16x8*)(Bs + (wn * 64 + n * 16 + l15) * 64 + ks * 32 + l4 * 8);
            #pragma unroll
            for (int m = 0; m < 4; ++m)
                #pragma unroll
                for (int n = 0; n < 4; ++n)
                    acc[m][n] = __builtin_amdgcn_mfma_f32_16x16x32_f16(af[m], bfr[n], acc[m][n], 0, 0, 0);
        }
        __syncthreads();
    }
    #pragma unroll
    for (int n = 0; n < 4; ++n) {
        int j = wn * 64 + n * 16 + l15;
        bool jok = j < Nout;
        float bv = jok ? bias[j] : 0.f;
        #pragma unroll
        for (int m = 0; m < 4; ++m) {
            int i0 = bm * 128 + wm * 64 + m * 16 + l4 * 4;
            #pragma unroll
            for (int r = 0; r < 4; ++r) {
                if (jok) C[(size_t)(i0 + r) * Nout + j] = acc[m][n][r] + bv;
            }
        }
    }
}

extern "C" void kernel_launch(void* const* d_in, const int* in_sizes, int n_in,
                              void* d_out, int out_size, void* d_ws, size_t ws_size,
                              hipStream_t stream) {
    const float* x  = (const float*)d_in[0];
    const float* W1 = (const float*)d_in[1];
    const float* b1 = (const float*)d_in[2];
    const float* W2 = (const float*)d_in[3];
    const float* b2 = (const float*)d_in[4];
    const float* W3 = (const float*)d_in[5];
    const float* b3 = (const float*)d_in[6];
    const float* W4 = (const float*)d_in[7];
    const float* b4 = (const float*)d_in[8];
    const float* W5 = (const float*)d_in[9];
    const float* b5 = (const float*)d_in[10];
    const void* m1 = d_in[11];
    const void* m2 = d_in[12];
    const void* m3 = d_in[13];
    const void* m4 = d_in[14];

    char* ws = (char*)d_ws;
    size_t off = 0;
    auto alloc = [&](size_t b) { char* p = ws + off; off += (b + 255) & ~(size_t)255; return p; };
    f16* xb  = (f16*)alloc((size_t)BATCH * INDP * 2);
    f16* w1b = (f16*)alloc((size_t)HID * INDP * 2);
    f16* w2b = (f16*)alloc((size_t)HID * HID * 2);
    f16* w3b = (f16*)alloc((size_t)HID * HID * 2);
    f16* w4b = (f16*)alloc((size_t)HID * HID * 2);
    f16* w5b = (f16*)alloc((size_t)128 * HID * 2);
    f16* h1  = (f16*)alloc((size_t)BATCH * HID * 2);
    f16* h2  = (f16*)alloc((size_t)BATCH * HID * 2);
    int* flags = (int*)alloc(256);

    hipMemsetAsync(flags, 0, sizeof(int), stream);
    mask_detect<<<64, 256, 0, stream>>>((const unsigned char*)m1, 262144, flags);

    auto prep = [&](const float* src, const void* mk, f16* dst,
                    int rin, int kin, int kout, int rout) {
        int total = rout * kout;
        prep_cast<<<(total + 255) / 256, 256, 0, stream>>>(src, mk, flags, dst,
                                                           rin, kin, kout, total);
    };
    prep(x,  nullptr, xb,  BATCH, IND, INDP, BATCH);
    prep(W1, m1,      w1b, HID,   IND, INDP, HID);
    prep(W2, m2,      w2b, HID,   HID, HID,  HID);
    prep(W3, m3,      w3b, HID,   HID, HID,  HID);
    prep(W4, m4,      w4b, HID,   HID, HID,  HID);
    prep(W5, nullptr, w5b, OUTD,  HID, HID,  128);

    int g8 = (BATCH / 256) * (HID / 256);   // 64 * 8 = 512 blocks
    gemm8p<true><<<g8, 512, 0, stream>>>(xb, w1b, b1, h1, HID, INDP);
    gemm8p<true><<<g8, 512, 0, stream>>>(h1, w2b, b2, h2, HID, HID);
    gemm8p<true><<<g8, 512, 0, stream>>>(h2, w3b, b3, h1, HID, HID);
    gemm8p<true><<<g8, 512, 0, stream>>>(h1, w4b, b4, h2, HID, HID);
    gemm_head<<<BATCH / 128, 256, 0, stream>>>(h2, w5b, b5, (float*)d_out, HID, OUTD);
}

// Round 7
// 558.291 us; speedup vs baseline: 1.2032x; 1.0477x over previous
//
#include <hip/hip_runtime.h>
#include <hip/hip_bf16.h>
#include <hip/hip_fp16.h>

#define BATCH 16384
#define HID   2048
#define IND   784
#define INDP  896   // 784 padded to 14*64 (even # of 64-wide K-tiles)
#define OUTD  10

typedef _Float16 f16;
typedef __attribute__((ext_vector_type(8))) _Float16 f16x8;
typedef __attribute__((ext_vector_type(4))) float f32x4;

// ---- mask dtype detector (verified R5) -------------------------------------
__global__ void mask_detect(const unsigned char* __restrict__ p, int nbytes,
                            int* __restrict__ flags) {
    int acc = 0;
    for (int i = blockIdx.x * blockDim.x + threadIdx.x; i < nbytes;
         i += gridDim.x * blockDim.x) {
        unsigned char b = p[i];
        if (b > 1) acc |= 2;
        else if (b != 0 && (i & 3) != 0) acc |= 1;
    }
    if (acc) atomicOr(flags, acc);
}

__global__ void prep_cast(const float* __restrict__ W,
                          const void* __restrict__ Mk,
                          const int* __restrict__ flags,
                          f16* __restrict__ out,
                          int rin, int kin, int kout, int total) {
    int idx = blockIdx.x * blockDim.x + threadIdx.x;
    if (idx >= total) return;
    int r = idx / kout, c = idx - r * kout;
    float v = 0.f;
    if (r < rin && c < kin) {
        v = W[(size_t)r * kin + c];
        if (Mk) {
            size_t mi = (size_t)r * kin + c;
            bool byteMode = (*flags == 1);
            bool keep = byteMode ? (((const unsigned char*)Mk)[mi] != 0)
                                 : (((const unsigned int*)Mk)[mi] != 0u);
            if (!keep) v = 0.f;
        }
    }
    out[idx] = (f16)v;
}

__device__ __forceinline__ void gload_lds16(const f16* g, f16* l) {
    __builtin_amdgcn_global_load_lds(
        (const __attribute__((address_space(1))) unsigned int*)g,
        (__attribute__((address_space(3))) unsigned int*)l,
        16, 0, 0);
}

#define BAR()   __builtin_amdgcn_s_barrier()
#define SCHED() __builtin_amdgcn_sched_barrier(0)
#define WAITV4() asm volatile("s_waitcnt vmcnt(4)" ::: "memory")
#define WAITL0() asm volatile("s_waitcnt lgkmcnt(0)" ::: "memory")

// ---- 256x256 8-phase GEMM (T1+T2+T3+T4+T5), C[M][N] = A@B^T + bias, ReLU ---
// BM=BN=256, BK=64, 8 waves (2Mx4N), 512 thr. LDS: A/B x [buf][ks][256][32] f16
// = 128 KiB. Panel = [256][32] (16 KB, 2 gload_lds/phase).
// Swizzle (R7): 16B-slot ^= (row>>1)&3, pre-swizzled on global src, applied on
// ds_read (involution). Bank-position p = (row&1)*4 + slot: consecutive 8 lanes
// (l15=0..7, fixed l4) now cover all 8 positions (even/odd l15 each map f
// bijectively onto {0..3}) -> conflict-free b128 reads. R6's f=row&3 left
// l15 and l15+4 colliding (4-way residual, 1.26e7 conflict-cycles measured).
template<bool RELU>
__global__ __launch_bounds__(512, 2) void gemm8p(
    const f16* __restrict__ A, const f16* __restrict__ B,
    const float* __restrict__ bias, f16* __restrict__ C,
    int N, int K) {
    __shared__ f16 As[2 * 2 * 256 * 32];
    __shared__ f16 Bs[2 * 2 * 256 * 32];

    int nbn = N >> 8;
    int nwg = gridDim.x;
    int cpx = nwg >> 3;                       // nwg % 8 == 0 here
    int bid = blockIdx.x;
    int swz = (bid & 7) * cpx + (bid >> 3);   // XCD-aware, bijective
    int bm = swz / nbn, bn = swz % nbn;

    int tid = threadIdx.x;
    int w = tid >> 6, lane = tid & 63;
    int wr = w >> 2, wc = w & 3;
    int l15 = lane & 15, l4 = lane >> 4;

    const f16* Ag = A + (size_t)bm * 256 * K;
    const f16* Bg = B + (size_t)bn * 256 * K;

    // staging geometry: issue j slot fs=j*512+tid -> row=fs>>2, s=fs&3;
    // global col-slot = s ^ ((row>>1)&3) (inverse swizzle on source;
    // rows r0 and r0+128 share (r0>>1)&3 since 128>>1=64 ≡ 0 mod 4).
    int r0 = tid >> 2, s0 = tid & 3;
    int c0 = (s0 ^ ((r0 >> 1) & 3)) * 8;
    int ldsw0 = (w * 64) * 8;                 // wave-uniform LDS f16 offsets
    int ldsw1 = (512 + w * 64) * 8;

    auto stageA = [&](int buf, int ks, int tk) {
        const f16* s = Ag + (size_t)r0 * K + tk * 64 + ks * 32 + c0;
        gload_lds16(s, As + (buf * 2 + ks) * 8192 + ldsw0);
        const f16* s2 = Ag + (size_t)(128 + r0) * K + tk * 64 + ks * 32 + c0;
        gload_lds16(s2, As + (buf * 2 + ks) * 8192 + ldsw1);
    };
    auto stageB = [&](int buf, int ks, int tk) {
        const f16* s = Bg + (size_t)r0 * K + tk * 64 + ks * 32 + c0;
        gload_lds16(s, Bs + (buf * 2 + ks) * 8192 + ldsw0);
        const f16* s2 = Bg + (size_t)(128 + r0) * K + tk * 64 + ks * 32 + c0;
        gload_lds16(s2, Bs + (buf * 2 + ks) * 8192 + ldsw1);
    };

    int rsw = (l4 ^ ((l15 >> 1) & 3)) * 8;    // swizzled read slot (f16 units)
    auto ldA = [&](f16x8 (&af)[4], int buf, int ks, int mh) {
        int base = (buf * 2 + ks) * 8192;
        #pragma unroll
        for (int m = 0; m < 4; ++m) {
            int row = wr * 128 + (mh * 4 + m) * 16 + l15;
            af[m] = *(const f16x8*)(As + base + row * 32 + rsw);
        }
    };
    auto ldB = [&](f16x8 (&bf)[4], int buf, int ks) {
        int base = (buf * 2 + ks) * 8192;
        #pragma unroll
        for (int n = 0; n < 4; ++n) {
            int row = wc * 64 + n * 16 + l15;
            bf[n] = *(const f16x8*)(Bs + base + row * 32 + rsw);
        }
    };

    f32x4 acc[8][4] = {};
    auto mma = [&](f16x8 (&af)[4], f16x8 (&bf)[4], int mh) {
        __builtin_amdgcn_s_setprio(1);
        #pragma unroll
        for (int m = 0; m < 4; ++m)
            #pragma unroll
            for (int n = 0; n < 4; ++n)
                acc[mh * 4 + m][n] = __builtin_amdgcn_mfma_f32_16x16x32_f16(
                    af[m], bf[n], acc[mh * 4 + m][n], 0, 0, 0);
        __builtin_amdgcn_s_setprio(0);
    };

    int NT = K >> 6, NI = NT >> 1;

    // prologue: tile0 all panels, tile1 A0,B0 (12 issues); oldest 8 must land
    stageA(0, 0, 0); stageB(0, 0, 0); stageA(0, 1, 0); stageB(0, 1, 0);
    stageA(1, 0, 1); stageB(1, 0, 1);
    WAITV4(); SCHED(); BAR();

    for (int it = 0; it < NI; ++it) {
        int t1 = 2 * it + 1, t2 = 2 * it + 2, t3 = 2 * it + 3;
        if (t2 >= NT) t2 = 0;   // tail: stage into retired panels, never read
        if (t3 >= NT) t3 = 0;
        f16x8 a0[4], a1[4], b0[4], b1[4];

        // ph1: buf0 ks0 mh0 | stage buf1.A1 <- t1
        ldA(a0, 0, 0, 0); ldB(b0, 0, 0); stageA(1, 1, t1);
        SCHED(); BAR(); WAITL0(); SCHED();
        mma(a0, b0, 0); BAR();
        // ph2: buf0 ks0 mh1 (reuse b0) | stage buf1.B1 <- t1
        ldA(a1, 0, 0, 1); stageB(1, 1, t1);
        SCHED(); BAR(); WAITL0(); SCHED();
        mma(a1, b0, 1); BAR();
        // ph3: buf0 ks1 mh0 | stage buf0.A0 <- t2
        ldA(a0, 0, 1, 0); ldB(b1, 0, 1); stageA(0, 0, t2);
        SCHED(); BAR(); WAITL0(); SCHED();
        mma(a0, b1, 0); BAR();
        // ph4: buf0 ks1 mh1 | stage buf0.B0 <- t2 | vmcnt(4)
        ldA(a1, 0, 1, 1); stageB(0, 0, t2);
        SCHED(); BAR(); WAITL0(); SCHED();
        mma(a1, b1, 1); WAITV4(); SCHED(); BAR();
        // ph5: buf1 ks0 mh0 | stage buf0.A1 <- t2
        ldA(a0, 1, 0, 0); ldB(b0, 1, 0); stageA(0, 1, t2);
        SCHED(); BAR(); WAITL0(); SCHED();
        mma(a0, b0, 0); BAR();
        // ph6: buf1 ks0 mh1 | stage buf0.B1 <- t2
        ldA(a1, 1, 0, 1); stageB(0, 1, t2);
        SCHED(); BAR(); WAITL0(); SCHED();
        mma(a1, b0, 1); BAR();
        // ph7: buf1 ks1 mh0 | stage buf1.A0 <- t3
        ldA(a0, 1, 1, 0); ldB(b1, 1, 1); stageA(1, 0, t3);
        SCHED(); BAR(); WAITL0(); SCHED();
        mma(a0, b1, 0); BAR();
        // ph8: buf1 ks1 mh1 | stage buf1.B0 <- t3 | vmcnt(4)
        ldA(a1, 1, 1, 1); stageB(1, 0, t3);
        SCHED(); BAR(); WAITL0(); SCHED();
        mma(a1, b1, 1); WAITV4(); SCHED(); BAR();
    }

    // epilogue: C/D layout col=lane&15, row=(lane>>4)*4+reg (m89/m91)
    #pragma unroll
    for (int nf = 0; nf < 4; ++nf) {
        int j = bn * 256 + wc * 64 + nf * 16 + l15;
        float bv = bias[j];
        #pragma unroll
        for (int mf = 0; mf < 8; ++mf) {
            int i0 = bm * 256 + wr * 128 + mf * 16 + l4 * 4;
            #pragma unroll
            for (int r = 0; r < 4; ++r) {
                float v = acc[mf][nf][r] + bv;
                if (RELU) v = fmaxf(v, 0.f);
                C[(size_t)(i0 + r) * N + j] = (f16)v;
            }
        }
    }
}

// ---- head: verified R5 128^2 kernel (Nout=10 guard, f32 out) ---------------
__global__ __launch_bounds__(256, 3) void gemm_head(
    const f16* __restrict__ A, const f16* __restrict__ B,
    const float* __restrict__ bias, float* __restrict__ C,
    int K, int Nout) {
    __shared__ f16 As[128 * 64];
    __shared__ f16 Bs[128 * 64];
    int bm = blockIdx.x;
    int t = threadIdx.x;
    int w = t >> 6, lane = t & 63;
    int wm = w >> 1, wn = w & 1;
    int l15 = lane & 15, l4 = lane >> 4;
    const f16* Ag = A + (size_t)bm * 128 * K;
    const f16* Bg = B;
    int rr = w * 8 + (lane >> 3);
    int cc = (lane & 7) * 8;
    f32x4 acc[4][4] = {};
    for (int k0 = 0; k0 < K; k0 += 64) {
        #pragma unroll
        for (int i = 0; i < 4; ++i)
            gload_lds16(Ag + (size_t)(i * 32 + rr) * K + k0 + cc, As + i * 2048 + w * 512);
        #pragma unroll
        for (int i = 0; i < 4; ++i)
            gload_lds16(Bg + (size_t)(i * 32 + rr) * K + k0 + cc, Bs + i * 2048 + w * 512);
        __syncthreads();
        #pragma unroll
        for (int ks = 0; ks < 2; ++ks) {
            f16x8 af[4], bfr[4];
            #pragma unroll
            for (int m = 0; m < 4; ++m)
                af[m] = *(const f16x8*)(As + (wm * 64 + m * 16 + l15) * 64 + ks * 32 + l4 * 8);
            #pragma unroll
            for (int n = 0; n < 4; ++n)
                bfr[n] = *(const f16x8*)(Bs + (wn * 64 + n * 16 + l15) * 64 + ks * 32 + l4 * 8);
            #pragma unroll
            for (int m = 0; m < 4; ++m)
                #pragma unroll
                for (int n = 0; n < 4; ++n)
                    acc[m][n] = __builtin_amdgcn_mfma_f32_16x16x32_f16(af[m], bfr[n], acc[m][n], 0, 0, 0);
        }
        __syncthreads();
    }
    #pragma unroll
    for (int n = 0; n < 4; ++n) {
        int j = wn * 64 + n * 16 + l15;
        bool jok = j < Nout;
        float bv = jok ? bias[j] : 0.f;
        #pragma unroll
        for (int m = 0; m < 4; ++m) {
            int i0 = bm * 128 + wm * 64 + m * 16 + l4 * 4;
            #pragma unroll
            for (int r = 0; r < 4; ++r) {
                if (jok) C[(size_t)(i0 + r) * Nout + j] = acc[m][n][r] + bv;
            }
        }
    }
}

extern "C" void kernel_launch(void* const* d_in, const int* in_sizes, int n_in,
                              void* d_out, int out_size, void* d_ws, size_t ws_size,
                              hipStream_t stream) {
    const float* x  = (const float*)d_in[0];
    const float* W1 = (const float*)d_in[1];
    const float* b1 = (const float*)d_in[2];
    const float* W2 = (const float*)d_in[3];
    const float* b2 = (const float*)d_in[4];
    const float* W3 = (const float*)d_in[5];
    const float* b3 = (const float*)d_in[6];
    const float* W4 = (const float*)d_in[7];
    const float* b4 = (const float*)d_in[8];
    const float* W5 = (const float*)d_in[9];
    const float* b5 = (const float*)d_in[10];
    const void* m1 = d_in[11];
    const void* m2 = d_in[12];
    const void* m3 = d_in[13];
    const void* m4 = d_in[14];

    char* ws = (char*)d_ws;
    size_t off = 0;
    auto alloc = [&](size_t b) { char* p = ws + off; off += (b + 255) & ~(size_t)255; return p; };
    f16* xb  = (f16*)alloc((size_t)BATCH * INDP * 2);
    f16* w1b = (f16*)alloc((size_t)HID * INDP * 2);
    f16* w2b = (f16*)alloc((size_t)HID * HID * 2);
    f16* w3b = (f16*)alloc((size_t)HID * HID * 2);
    f16* w4b = (f16*)alloc((size_t)HID * HID * 2);
    f16* w5b = (f16*)alloc((size_t)128 * HID * 2);
    f16* h1  = (f16*)alloc((size_t)BATCH * HID * 2);
    f16* h2  = (f16*)alloc((size_t)BATCH * HID * 2);
    int* flags = (int*)alloc(256);

    hipMemsetAsync(flags, 0, sizeof(int), stream);
    mask_detect<<<64, 256, 0, stream>>>((const unsigned char*)m1, 262144, flags);

    auto prep = [&](const float* src, const void* mk, f16* dst,
                    int rin, int kin, int kout, int rout) {
        int total = rout * kout;
        prep_cast<<<(total + 255) / 256, 256, 0, stream>>>(src, mk, flags, dst,
                                                           rin, kin, kout, total);
    };
    prep(x,  nullptr, xb,  BATCH, IND, INDP, BATCH);
    prep(W1, m1,      w1b, HID,   IND, INDP, HID);
    prep(W2, m2,      w2b, HID,   HID, HID,  HID);
    prep(W3, m3,      w3b, HID,   HID, HID,  HID);
    prep(W4, m4,      w4b, HID,   HID, HID,  HID);
    prep(W5, nullptr, w5b, OUTD,  HID, HID,  128);

    int g8 = (BATCH / 256) * (HID / 256);   // 64 * 8 = 512 blocks
    gemm8p<true><<<g8, 512, 0, stream>>>(xb, w1b, b1, h1, HID, INDP);
    gemm8p<true><<<g8, 512, 0, stream>>>(h1, w2b, b2, h2, HID, HID);
    gemm8p<true><<<g8, 512, 0, stream>>>(h2, w3b, b3, h1, HID, HID);
    gemm8p<true><<<g8, 512, 0, stream>>>(h1, w4b, b4, h2, HID, HID);
    gemm_head<<<BATCH / 128, 256, 0, stream>>>(h2, w5b, b5, (float*)d_out, HID, OUTD);
}